// Round 7
// baseline (164.543 us; speedup 1.0000x reference)
//
#include <hip/hip_runtime.h>
#include <stdint.h>

typedef __attribute__((ext_vector_type(8))) short short8;     // bf16x8 MFMA frag (4 VGPR)
typedef __attribute__((ext_vector_type(4))) float floatx4;
typedef __attribute__((ext_vector_type(4))) unsigned int uintx4;
typedef __attribute__((ext_vector_type(2))) unsigned int uintx2;

#define S_LEN 2048
#define NHEAD 16
#define DHEAD 64
#define KB    64
#define NTILE 32                              // S_LEN / KB
#define PL_BYTES (S_LEN * DHEAD * 2)          // 262144 bf16 bytes per (b,h) plane
#define VOFF  (2 * NHEAD * PL_BYTES)          // 8388608
#define MOFF  (2 * VOFF)                      // 16777216  (mask frags: 2 b x 4096 B)
#define PO0   (MOFF + 8192)                   // O partials half 0: 256 slots x 64KB
#define PO1   (PO0 + 256 * 65536)
#define DN0   (PO1 + 256 * 65536)             // den partials: 256 slots x 1KB
#define DN1   (DN0 + 262144)
#define WS_NEEDED ((size_t)DN1 + 262144)
#define NEGINF (-__builtin_inff())
#define LOG2E 1.4426950408889634f

#define GLOAD_LDS16(gp, lp) \
    __builtin_amdgcn_global_load_lds((const __attribute__((address_space(1))) unsigned int*)(gp), \
                                     (__attribute__((address_space(3))) unsigned int*)(lp), 16, 0, 0)

static __device__ __forceinline__ unsigned f2bf(float f) {
    union { float f; unsigned u; } w; w.f = f;
    return (w.u + 0x7FFFu + ((w.u >> 16) & 1u)) >> 16;   // RNE f32->bf16
}

static __device__ __forceinline__ unsigned cvtpk(float lo, float hi) {
    unsigned r;
    asm("v_cvt_pk_bf16_f32 %0, %1, %2" : "=v"(r) : "v"(lo), "v"(hi));
    return r;                                             // [hi_bf16 | lo_bf16]
}

static __device__ __forceinline__ floatx4 mfma16(short8 a, short8 b, floatx4 c) {
    return __builtin_amdgcn_mfma_f32_16x16x32_bf16(a, b, c, 0, 0, 0);
}

// ---------------------------------------------------------------------------
// Prepass (unchanged): K -> bf16 row-major pre-swizzled; V -> bf16 TRANSPOSED
// [d][pkey] (per-32 key interleave p=8a+i -> key 16(i>>2)+4a+(i&3)),
// pad-masked V rows ZEROED; mask -> bf16 0/1 frags in PV order (128 B/tile).
// Swizzle (K,V planes): byte ^= (row&7)<<4 within 128B rows.
// ---------------------------------------------------------------------------
__global__ __launch_bounds__(256) void prep_kernel(
    const float* __restrict__ kg, const float* __restrict__ vg,
    const int* __restrict__ mg, char* __restrict__ ws)
{
    __shared__ unsigned short Tl[64 * 72];    // transposed V tile, padded stride
    const int bid = blockIdx.x;               // 0..1023
    const int t   = bid & 31;                 // key tile
    const int bh  = bid >> 5;
    const int b   = bh >> 4, h = bh & 15;
    const int tid = threadIdx.x;
    char* kpre = ws + (size_t)bh * PL_BYTES;
    char* vpre = ws + VOFF + (size_t)bh * PL_BYTES;

    // K: convert + swizzled store (thread -> 32B of output)
    {
        const int r  = tid >> 2;              // key row in tile
        const int c0 = (tid & 3) * 32;
        const int X  = (r & 7) << 4;
        const size_t grow = (((size_t)b * S_LEN + t * 64 + r) * NHEAD + h) * DHEAD;
        #pragma unroll
        for (int cc = 0; cc < 2; ++cc) {
            const int c  = c0 + 16 * cc;
            const int d0 = (c ^ X) >> 1;
            floatx4 f0 = *(const floatx4*)(kg + grow + d0);
            floatx4 f1 = *(const floatx4*)(kg + grow + d0 + 4);
            uintx4 pk = (uintx4){ f2bf(f0[0]) | (f2bf(f0[1]) << 16),
                                  f2bf(f0[2]) | (f2bf(f0[3]) << 16),
                                  f2bf(f1[0]) | (f2bf(f1[1]) << 16),
                                  f2bf(f1[2]) | (f2bf(f1[3]) << 16) };
            *(uintx4*)(kpre + t * 8192 + r * 128 + c) = pk;
        }
    }
    // V: load rows coalesced, zero pad-masked rows, transpose into LDS
    {
        const int key = tid >> 2;
        const int d0  = (tid & 3) * 16;
        const float vz = mg[(size_t)b * S_LEN + t * 64 + key] ? 1.f : 0.f;
        const size_t grow = (((size_t)b * S_LEN + t * 64 + key) * NHEAD + h) * DHEAD;
        #pragma unroll
        for (int q = 0; q < 4; ++q) {
            floatx4 f = *(const floatx4*)(vg + grow + d0 + 4 * q);
            #pragma unroll
            for (int ii = 0; ii < 4; ++ii)
                Tl[(d0 + 4 * q + ii) * 72 + key] = (unsigned short)f2bf(f[ii] * vz);
        }
    }
    __syncthreads();
    // V out: swizzled 16B chunks, keys gathered in interleaved storage order
    {
        const int d  = tid >> 2;
        const int c0 = (tid & 3) * 32;
        const int Xv = (d & 7) << 4;
        #pragma unroll
        for (int cc = 0; cc < 2; ++cc) {
            const int c   = c0 + 16 * cc;      // physical byte pos in 128B row
            const int pp0 = (c ^ Xv) >> 1;     // logical halfword pos (mult of 8)
            const int blk = pp0 >> 5;
            const int a   = (pp0 & 31) >> 3;
            unsigned short vals[8];
            #pragma unroll
            for (int i = 0; i < 8; ++i) {
                const int key = 32 * blk + ((i < 4) ? (4 * a + i) : (16 + 4 * a + i - 4));
                vals[i] = Tl[d * 72 + key];
            }
            *(uintx4*)(vpre + t * 8192 + d * 128 + c) = *(const uintx4*)vals;
        }
    }
    // mask frags: bf16 1.0/0.0 at slot (g,ks,i) matching pa's key map
    if (h == 0 && tid < 64) {
        const int key = tid;
        const int gg = (key >> 2) & 3, lo = key & 3;
        const int ks = key >> 5,      hi = (key >> 4) & 1;
        const unsigned short mv = mg[(size_t)b * S_LEN + t * 64 + key] ? 0x3F80 : 0;
        *(unsigned short*)(ws + MOFF + (size_t)b * 4096 + t * 128
                           + gg * 32 + ks * 16 + (4 * hi + lo) * 2) = mv;
    }
}

// ---------------------------------------------------------------------------
// Main: 256 q-rows/block, 8 waves = 4wq x 2kh, grp=4 (wave: 64 q x 32 keys).
// Key-range split in two half-blocks (additive partials -> ws).
// Fixed-max softmax (m=8 in acc init); den via mask-MFMA.
// Pairing: bid & bid+256 -> (qb,h0) & (7-qb,h1): every CU sums 18 tiles.
// ---------------------------------------------------------------------------
__global__ __launch_bounds__(512, 4) void fa3_main(
    const float* __restrict__ qg, char* __restrict__ ws)
{
    __shared__ char smem[65536];
    unsigned short* Qs = (unsigned short*)smem;          // 32 KB [256*64]
    char* KsB = smem + 32768;                            // 2 x 8 KB (dbuf)
    char* VsB = smem + 49152;                            // 2 x 8 KB (dbuf)

    const int tid  = threadIdx.x;
    const int bid  = blockIdx.x;
    const int half = bid >> 8;
    const int r256 = bid & 255;
    const int qb   = half ? (7 - (r256 >> 5)) : (r256 >> 5);
    const int bh   = r256 & 31;
    const int b    = bh >> 4;
    const int h    = bh & 15;
    const int w    = tid >> 6;               // wave 0..7
    const int lane = tid & 63;
    const int g    = lane >> 4;
    const int lm   = lane & 15;
    const int kh   = w >> 2;                 // key half 0/1 (32 keys)
    const int wq   = w & 3;                  // q quarter: rows [64wq, 64wq+64)
    const char* kpre = ws + (size_t)bh * PL_BYTES;
    const char* vpre = ws + VOFF + (size_t)bh * PL_BYTES;
    const char* mgf  = ws + MOFF + (size_t)b * 4096;
    const int H   = 2 * qb + 2;              // tiles per half
    const int kt0 = half * H, kt1 = kt0 + H;
    const int slot = qb * 32 + bh;

    // stage first tile (one 16B DMA per thread per plane)
    GLOAD_LDS16(kpre + (size_t)kt0 * 8192 + tid * 16, KsB + tid * 16);
    GLOAD_LDS16(vpre + (size_t)kt0 * 8192 + tid * 16, VsB + tid * 16);

    // stage Q: load fp32, L2-normalize * 0.125 * log2(e), bf16, swizzled
    #pragma unroll
    for (int rr = 0; rr < 2; ++rr) {
        const int r  = rr * 128 + (tid >> 2);  // q-row 0..255
        const int q0 = tid & 3;
        const float* src = qg + (((size_t)b * S_LEN + (size_t)qb * 256 + r) * NHEAD + h) * DHEAD + q0 * 16;
        floatx4 f0 = *(const floatx4*)(src + 0);
        floatx4 f1 = *(const floatx4*)(src + 4);
        floatx4 f2 = *(const floatx4*)(src + 8);
        floatx4 f3 = *(const floatx4*)(src + 12);
        float ssq = 0.f;
        #pragma unroll
        for (int i = 0; i < 4; ++i)
            ssq += f0[i]*f0[i] + f1[i]*f1[i] + f2[i]*f2[i] + f3[i]*f3[i];
        ssq += __shfl_xor(ssq, 1);
        ssq += __shfl_xor(ssq, 2);
        const float sc = (0.125f * LOG2E) / fmaxf(sqrtf(ssq), 1e-12f);
        float fv[16];
        #pragma unroll
        for (int i = 0; i < 4; ++i) { fv[i]=f0[i]; fv[4+i]=f1[i]; fv[8+i]=f2[i]; fv[12+i]=f3[i]; }
        unsigned pk[8];
        #pragma unroll
        for (int i = 0; i < 8; ++i)
            pk[i] = cvtpk(fv[2*i]*sc, fv[2*i+1]*sc);
        const int X = (r & 7) << 4;
        char* qp = (char*)Qs + r * 128;
        *(uintx4*)(qp + ((32*q0)      ^ X)) = (uintx4){pk[0],pk[1],pk[2],pk[3]};
        *(uintx4*)(qp + ((32*q0 + 16) ^ X)) = (uintx4){pk[4],pk[5],pk[6],pk[7]};
    }
    asm volatile("s_waitcnt vmcnt(0)" ::: "memory");   // first tile's DMA done
    __syncthreads();                                    // Qs + tile visible

    const int Xl = (lm & 7) << 4;
    // per-lane Q fragments: 4 q-groups (rows 64wq+16grp+lm), contiguous d-map
    short8 qf[4][2];
    #pragma unroll
    for (int grp = 0; grp < 4; ++grp) {
        const int row = wq * 64 + grp * 16 + lm;
        const char* base = (const char*)Qs + row * 128;
        #pragma unroll
        for (int ksd = 0; ksd < 2; ++ksd)
            qf[grp][ksd] = *(const short8*)(base + ((64*ksd + 16*g) ^ Xl));
    }

    floatx4 oacc[4][4];
    floatx4 dacc[4];
    #pragma unroll
    for (int grp = 0; grp < 4; ++grp) {
        dacc[grp] = (floatx4){0.f,0.f,0.f,0.f};
        #pragma unroll
        for (int nt = 0; nt < 4; ++nt) oacc[grp][nt] = (floatx4){0.f,0.f,0.f,0.f};
    }
    const int qwmin = qb * 256 + wq * 64;

    int cur = 0;
    for (int kt = kt0; kt < kt1; ++kt) {
        // issue next tile's DMA (hidden under this tile's compute)
        if (kt + 1 < kt1) {
            const size_t tb = (size_t)(kt + 1) * 8192;
            GLOAD_LDS16(kpre + tb + tid * 16, KsB + (cur ^ 1) * 8192 + tid * 16);
            GLOAD_LDS16(vpre + tb + tid * 16, VsB + (cur ^ 1) * 8192 + tid * 16);
        }
        // mask fragment for this wave's 32 keys (uniform per (g,kh), L2-hit)
        const short8 mf = *(const short8*)(mgf + kt * 128 + g * 32 + kh * 16);

        // ---- swapped QK^T on this wave's key half; acc init -8 ----
        floatx4 st[4][2];
        #pragma unroll
        for (int grp = 0; grp < 4; ++grp)
            #pragma unroll
            for (int mt = 0; mt < 2; ++mt) st[grp][mt] = (floatx4){-8.f,-8.f,-8.f,-8.f};
        const char* kbase = KsB + cur * 8192 + kh * 4096 + lm * 128;
        __builtin_amdgcn_s_setprio(1);
        #pragma unroll
        for (int ksd = 0; ksd < 2; ++ksd) {
            #pragma unroll
            for (int mt = 0; mt < 2; ++mt) {
                short8 kf = *(const short8*)(kbase + mt * 2048 + ((64*ksd + 16*g) ^ Xl));
                #pragma unroll
                for (int grp = 0; grp < 4; ++grp)
                    st[grp][mt] = mfma16(kf, qf[grp][ksd], st[grp][mt]);
            }
        }
        __builtin_amdgcn_s_setprio(0);

        // ---- V B-frags (shared by all 4 q-groups) ----
        short8 vf[4];
        {
            const char* vbase = VsB + cur * 8192 + lm * 128;
            #pragma unroll
            for (int nt = 0; nt < 4; ++nt)
                vf[nt] = *(const short8*)(vbase + nt * 2048 + ((64*kh + 16*g) ^ Xl));
        }

        // ---- causal (gated tiles only); first-128 exception folds away ----
        if ((kt * 64 + 63 > qwmin) && (qb > 0 || kt >= 2)) {
            #pragma unroll
            for (int grp = 0; grp < 4; ++grp) {
                const int qgl = qwmin + grp * 16 + lm;
                #pragma unroll
                for (int mt = 0; mt < 2; ++mt)
                    #pragma unroll
                    for (int j = 0; j < 4; ++j) {
                        const int kgl = kt * 64 + kh * 32 + mt * 16 + 4 * g + j;
                        if (kgl > qgl) st[grp][mt][j] = -10000.f;
                    }
            }
        }

        // ---- p = exp2(st); pack; den-MFMA + PV-MFMA per group ----
        short8 pa[4];
        #pragma unroll
        for (int grp = 0; grp < 4; ++grp) {
            float p[8];
            #pragma unroll
            for (int mt = 0; mt < 2; ++mt)
                #pragma unroll
                for (int j = 0; j < 4; ++j)
                    p[mt * 4 + j] = exp2f(st[grp][mt][j]);
            union { short8 s; uintx4 u; } pu;
            pu.u = (uintx4){ cvtpk(p[0], p[1]), cvtpk(p[2], p[3]),
                             cvtpk(p[4], p[5]), cvtpk(p[6], p[7]) };
            pa[grp] = pu.s;
        }
        __builtin_amdgcn_s_setprio(1);
        #pragma unroll
        for (int grp = 0; grp < 4; ++grp) {
            dacc[grp] = mfma16(pa[grp], mf, dacc[grp]);
            #pragma unroll
            for (int nt = 0; nt < 4; ++nt)
                oacc[grp][nt] = mfma16(pa[grp], vf[nt], oacc[grp][nt]);
        }
        __builtin_amdgcn_s_setprio(0);

        asm volatile("s_waitcnt vmcnt(0)" ::: "memory");  // next tile's DMA done
        __syncthreads();
        cur ^= 1;
    }

    // ---- combine key halves in LDS (64KB reuse), then store raw partials ----
    floatx4* rbuf = (floatx4*)smem;
    if (kh == 1) {
        #pragma unroll
        for (int grp = 0; grp < 4; ++grp)
            #pragma unroll
            for (int nt = 0; nt < 4; ++nt)
                rbuf[wq * 1024 + (grp * 4 + nt) * 64 + lane] = oacc[grp][nt];
    }
    __syncthreads();
    if (kh == 0) {
        #pragma unroll
        for (int grp = 0; grp < 4; ++grp)
            #pragma unroll
            for (int nt = 0; nt < 4; ++nt)
                oacc[grp][nt] += rbuf[wq * 1024 + (grp * 4 + nt) * 64 + lane];
    }
    __syncthreads();
    float* dbuf = (float*)smem;                 // 1 KB
    if (kh == 1 && lm == 0) {
        #pragma unroll
        for (int grp = 0; grp < 4; ++grp)
            #pragma unroll
            for (int j = 0; j < 4; ++j)
                dbuf[wq * 64 + grp * 16 + 4 * g + j] = dacc[grp][j];
    }
    __syncthreads();
    if (kh == 0) {
        float* po = (float*)(ws + (half ? PO1 : PO0) + (size_t)slot * 65536);
        float* pd = (float*)(ws + (half ? DN1 : DN0) + (size_t)slot * 1024);
        #pragma unroll
        for (int grp = 0; grp < 4; ++grp)
            #pragma unroll
            for (int j = 0; j < 4; ++j) {
                const int row = wq * 64 + grp * 16 + 4 * g + j;
                #pragma unroll
                for (int nt = 0; nt < 4; ++nt)
                    po[row * 64 + nt * 16 + lm] = oacc[grp][nt][j];
                if (lm == 0)
                    pd[row] = dacc[grp][j] + dbuf[row];
            }
    }
}

// ---------------------------------------------------------------------------
// Combine: out = (P0 + P1) / (D0 + D1), coalesced 8 f32 per thread.
// ---------------------------------------------------------------------------
__global__ __launch_bounds__(256) void fa3_combine(
    const char* __restrict__ ws, float* __restrict__ og)
{
    const int i0  = (blockIdx.x * 256 + threadIdx.x) * 8;
    const int d   = i0 & 63;
    int rem       = i0 >> 6;
    const int h   = rem & 15;  rem >>= 4;
    const int row = rem & 2047;
    const int b   = rem >> 11;
    const int qb  = row >> 8;
    const int q   = row & 255;
    const int slot = qb * 32 + b * 16 + h;
    const float* p0 = (const float*)(ws + PO0 + (size_t)slot * 65536) + q * 64 + d;
    const float* p1 = (const float*)(ws + PO1 + (size_t)slot * 65536) + q * 64 + d;
    const float den = ((const float*)(ws + DN0 + (size_t)slot * 1024))[q]
                    + ((const float*)(ws + DN1 + (size_t)slot * 1024))[q];
    const float inv = 1.0f / den;
    floatx4 a0 = *(const floatx4*)p0, a1 = *(const floatx4*)(p0 + 4);
    floatx4 b0 = *(const floatx4*)p1, b1 = *(const floatx4*)(p1 + 4);
    floatx4 o0, o1;
    #pragma unroll
    for (int i = 0; i < 4; ++i) { o0[i] = (a0[i] + b0[i]) * inv; o1[i] = (a1[i] + b1[i]) * inv; }
    *(floatx4*)(og + i0)     = o0;
    *(floatx4*)(og + i0 + 4) = o1;
}

// ---------------------------------------------------------------------------
// Fallback (round-2 kernel, known-good) if ws_size is too small.
// ---------------------------------------------------------------------------
__global__ __launch_bounds__(512) void fa3_fallback(
    const float* __restrict__ qg, const float* __restrict__ kg,
    const float* __restrict__ vg, const int* __restrict__ mg,
    float* __restrict__ og)
{
    __shared__ unsigned short Qs[128 * DHEAD];
    __shared__ unsigned short Ks2[KB * DHEAD];
    __shared__ unsigned short Vt[DHEAD * KB];
    __shared__ float Ms[KB];

    const int tid  = threadIdx.x;
    const int bid  = blockIdx.x;
    const int qb   = 15 - (bid >> 5);
    const int bh   = bid & 31;
    const int b    = bh >> 4;
    const int h    = bh & 15;
    const int w    = tid >> 6;
    const int lane = tid & 63;
    const int g    = lane >> 4;
    const int lm   = lane & 15;

    {
        const int r  = tid >> 2;
        const int q0 = tid & 3;
        const float* src = qg + (((size_t)b * S_LEN + (size_t)qb * 128 + r) * NHEAD + h) * DHEAD + q0 * 16;
        floatx4 f0 = *(const floatx4*)(src + 0);
        floatx4 f1 = *(const floatx4*)(src + 4);
        floatx4 f2 = *(const floatx4*)(src + 8);
        floatx4 f3 = *(const floatx4*)(src + 12);
        float ssq = 0.f;
        #pragma unroll
        for (int i = 0; i < 4; ++i)
            ssq += f0[i]*f0[i] + f1[i]*f1[i] + f2[i]*f2[i] + f3[i]*f3[i];
        ssq += __shfl_xor(ssq, 1);
        ssq += __shfl_xor(ssq, 2);
        const float sc = 0.125f / fmaxf(sqrtf(ssq), 1e-12f);
        float fv[16];
        #pragma unroll
        for (int i = 0; i < 4; ++i) { fv[i]=f0[i]; fv[4+i]=f1[i]; fv[8+i]=f2[i]; fv[12+i]=f3[i]; }
        unsigned pk[8];
        #pragma unroll
        for (int i = 0; i < 8; ++i)
            pk[i] = f2bf(fv[2*i]*sc) | (f2bf(fv[2*i+1]*sc) << 16);
        const int X = (r & 7) << 4;
        char* qp = (char*)Qs + r * 128;
        *(uintx4*)(qp + ((32*q0)      ^ X)) = (uintx4){pk[0],pk[1],pk[2],pk[3]};
        *(uintx4*)(qp + ((32*q0 + 16) ^ X)) = (uintx4){pk[4],pk[5],pk[6],pk[7]};
    }
    __syncthreads();

    short8 qf[2];
    {
        const int row = w * 16 + lm;
        const int X = (row & 7) << 4;
        const char* base = (const char*)Qs + row * 128;
        #pragma unroll
        for (int ks = 0; ks < 2; ++ks) {
            union { short8 s; uintx2 u[2]; } u;
            u.u[0] = *(const uintx2*)(base + ((64*ks + 8*g)      ^ X));
            u.u[1] = *(const uintx2*)(base + ((64*ks + 8*g + 32) ^ X));
            qf[ks] = u.s;
        }
    }

    floatx4 oacc[4];
    #pragma unroll
    for (int nt = 0; nt < 4; ++nt) oacc[nt] = (floatx4){0.f,0.f,0.f,0.f};
    float mrun = NEGINF, lrun = 0.f;
    const int q_glob = qb * 128 + w * 16 + lm;
    const int nkt = (qb == 0) ? 2 : (2 * qb + 2);

    for (int kt = 0; kt < nkt; ++kt) {
        const int kb0 = kt * KB;
        {
            const int r = tid >> 3;
            const int o = tid & 7;
            const size_t goff = (((size_t)b * S_LEN + kb0 + r) * NHEAD + h) * DHEAD + o * 8;
            floatx4 a0 = *(const floatx4*)(kg + goff);
            floatx4 a1 = *(const floatx4*)(kg + goff + 4);
            floatx4 c0 = *(const floatx4*)(vg + goff);
            floatx4 c1 = *(const floatx4*)(vg + goff + 4);
            uintx4 kw = (uintx4){ f2bf(a0[0]) | (f2bf(a0[1])<<16),
                                  f2bf(a0[2]) | (f2bf(a0[3])<<16),
                                  f2bf(a1[0]) | (f2bf(a1[1])<<16),
                                  f2bf(a1[2]) | (f2bf(a1[3])<<16) };
            *(uintx4*)((char*)Ks2 + r*128 + ((16*o) ^ ((r & 7) << 4))) = kw;
            float cv[8];
            #pragma unroll
            for (int i = 0; i < 4; ++i) { cv[i] = c0[i]; cv[4+i] = c1[i]; }
            #pragma unroll
            for (int i = 0; i < 8; ++i) {
                const int d = 8*o + i;
                Vt[d*64 + (r ^ (((i ^ o) & 7) << 3))] = (unsigned short)f2bf(cv[i]);
            }
            if (tid < KB) Ms[tid] = mg[(size_t)b * S_LEN + kb0 + tid] ? 0.f : NEGINF;
        }
        __syncthreads();

        floatx4 st[4];
        #pragma unroll
        for (int mt = 0; mt < 4; ++mt) st[mt] = (floatx4){0.f,0.f,0.f,0.f};
        #pragma unroll
        for (int ks = 0; ks < 2; ++ks) {
            #pragma unroll
            for (int mt = 0; mt < 4; ++mt) {
                const int row = mt * 16 + lm;
                const int X = (row & 7) << 4;
                const char* base = (const char*)Ks2 + row * 128;
                union { short8 s; uintx2 u[2]; } u;
                u.u[0] = *(const uintx2*)(base + ((64*ks + 8*g)      ^ X));
                u.u[1] = *(const uintx2*)(base + ((64*ks + 8*g + 32) ^ X));
                st[mt] = mfma16(u.s, qf[ks], st[mt]);
            }
        }

        const bool diag = (qb > 0) && (kt >= 2 * qb);
        float sv[16];
        #pragma unroll
        for (int mt = 0; mt < 4; ++mt) {
            #pragma unroll
            for (int j = 0; j < 4; ++j) {
                const int kl = mt * 16 + 4 * g + j;
                float s = st[mt][j] + Ms[kl];
                if (diag && (kb0 + kl > q_glob)) s = NEGINF;
                sv[mt * 4 + j] = s;
            }
        }

        float rmax = sv[0];
        #pragma unroll
        for (int i = 1; i < 16; ++i) rmax = fmaxf(rmax, sv[i]);
        rmax = fmaxf(rmax, __shfl_xor(rmax, 16));
        rmax = fmaxf(rmax, __shfl_xor(rmax, 32));
        const float mnew = fmaxf(mrun, rmax);
        const float cf = __expf(mrun - mnew);
        float p[16], psum = 0.f;
        #pragma unroll
        for (int i = 0; i < 16; ++i) { p[i] = __expf(sv[i] - mnew); psum += p[i]; }
        psum += __shfl_xor(psum, 16);
        psum += __shfl_xor(psum, 32);
        lrun = lrun * cf + psum;
        mrun = mnew;

        float cj[4];
        #pragma unroll
        for (int j = 0; j < 4; ++j) cj[j] = __shfl(cf, 20 * g + j);
        #pragma unroll
        for (int nt = 0; nt < 4; ++nt)
            #pragma unroll
            for (int j = 0; j < 4; ++j) oacc[nt][j] *= cj[j];

        short8 pa[2];
        #pragma unroll
        for (int ks = 0; ks < 2; ++ks)
            #pragma unroll
            for (int i = 0; i < 8; ++i)
                pa[ks][i] = (short)f2bf(p[(2*ks + (i>>2))*4 + (i&3)]);

        #pragma unroll
        for (int nt = 0; nt < 4; ++nt) {
            const int d = 16 * nt + lm;
            const int xz = (((d & 7) ^ ((d >> 3) & 7)) & 7) << 4;
            const char* vb = (const char*)Vt + d * 128;
            #pragma unroll
            for (int ks = 0; ks < 2; ++ks) {
                union { short8 s; uintx2 u[2]; } vu;
                vu.u[0] = *(const uintx2*)(vb + ((64*ks + 8*g)      ^ xz));
                vu.u[1] = *(const uintx2*)(vb + ((64*ks + 8*g + 32) ^ xz));
                oacc[nt] = mfma16(pa[ks], vu.s, oacc[nt]);
            }
        }
        __syncthreads();
    }

    const float inv = 1.0f / lrun;
    #pragma unroll
    for (int j = 0; j < 4; ++j) {
        const float invj = __shfl(inv, 20 * g + j);
        const int row = qb * 128 + w * 16 + 4 * g + j;
        float* dst = og + (((size_t)b * S_LEN + row) * NHEAD + h) * DHEAD + lm;
        #pragma unroll
        for (int nt = 0; nt < 4; ++nt) dst[nt * 16] = oacc[nt][j] * invj;
    }
}

extern "C" void kernel_launch(void* const* d_in, const int* in_sizes, int n_in,
                              void* d_out, int out_size, void* d_ws, size_t ws_size,
                              hipStream_t stream)
{
    const float* q = (const float*)d_in[0];
    const float* k = (const float*)d_in[1];
    const float* v = (const float*)d_in[2];
    const int*   m = (const int*)d_in[3];
    float* out = (float*)d_out;
    (void)in_sizes; (void)n_in; (void)out_size;
    if (ws_size >= WS_NEEDED) {
        prep_kernel<<<dim3(1024), dim3(256), 0, stream>>>(k, v, m, (char*)d_ws);
        fa3_main<<<dim3(512), dim3(512), 0, stream>>>(q, (char*)d_ws);
        fa3_combine<<<dim3(2048), dim3(256), 0, stream>>>((const char*)d_ws, out);
    } else {
        fa3_fallback<<<dim3(512), dim3(512), 0, stream>>>(q, k, v, m, out);
    }
}

// Round 8
// 51.283 us; speedup vs baseline: 3.2085x; 3.2085x over previous
//
#include <hip/hip_runtime.h>
#include <stdint.h>

typedef __attribute__((ext_vector_type(8))) short short8;     // bf16x8 MFMA frag (4 VGPR)
typedef __attribute__((ext_vector_type(4))) float floatx4;
typedef __attribute__((ext_vector_type(4))) unsigned int uintx4;
typedef __attribute__((ext_vector_type(2))) unsigned int uintx2;

#define S_LEN 2048
#define NHEAD 16
#define DHEAD 64
#define KB    64
#define NTILE 32                              // S_LEN / KB
#define PL_BYTES (S_LEN * DHEAD * 2)          // 262144 bf16 bytes per (b,h) plane
#define VOFF  (2 * NHEAD * PL_BYTES)          // 8388608
#define MOFF  (2 * VOFF)                      // 16777216  (mask frags: 2 b x 4096 B)
#define WS_NEEDED ((size_t)MOFF + 2 * 4096)
#define NEGINF (-__builtin_inff())
#define LOG2E 1.4426950408889634f

#define GLOAD_LDS16(gp, lp) \
    __builtin_amdgcn_global_load_lds((const __attribute__((address_space(1))) unsigned int*)(gp), \
                                     (__attribute__((address_space(3))) unsigned int*)(lp), 16, 0, 0)

static __device__ __forceinline__ unsigned f2bf(float f) {
    union { float f; unsigned u; } w; w.f = f;
    return (w.u + 0x7FFFu + ((w.u >> 16) & 1u)) >> 16;   // RNE f32->bf16
}

static __device__ __forceinline__ unsigned cvtpk(float lo, float hi) {
    unsigned r;
    asm("v_cvt_pk_bf16_f32 %0, %1, %2" : "=v"(r) : "v"(lo), "v"(hi));
    return r;                                             // [hi_bf16 | lo_bf16]
}

static __device__ __forceinline__ floatx4 mfma16(short8 a, short8 b, floatx4 c) {
    return __builtin_amdgcn_mfma_f32_16x16x32_bf16(a, b, c, 0, 0, 0);
}

// ---------------------------------------------------------------------------
// Prepass (unchanged): K -> bf16 row-major pre-swizzled; V -> bf16 TRANSPOSED
// [d][pkey] (per-32 key interleave p=8a+i -> key 16(i>>2)+4a+(i&3)),
// pad-masked V rows ZEROED; mask -> bf16 0/1 frags in PV order (128 B/tile).
// Swizzle (K,V planes): byte ^= (row&7)<<4 within 128B rows.
// ---------------------------------------------------------------------------
__global__ __launch_bounds__(256) void prep_kernel(
    const float* __restrict__ kg, const float* __restrict__ vg,
    const int* __restrict__ mg, char* __restrict__ ws)
{
    __shared__ unsigned short Tl[64 * 72];    // transposed V tile, padded stride
    const int bid = blockIdx.x;               // 0..1023
    const int t   = bid & 31;                 // key tile
    const int bh  = bid >> 5;
    const int b   = bh >> 4, h = bh & 15;
    const int tid = threadIdx.x;
    char* kpre = ws + (size_t)bh * PL_BYTES;
    char* vpre = ws + VOFF + (size_t)bh * PL_BYTES;

    // K: convert + swizzled store (thread -> 32B of output)
    {
        const int r  = tid >> 2;              // key row in tile
        const int c0 = (tid & 3) * 32;
        const int X  = (r & 7) << 4;
        const size_t grow = (((size_t)b * S_LEN + t * 64 + r) * NHEAD + h) * DHEAD;
        #pragma unroll
        for (int cc = 0; cc < 2; ++cc) {
            const int c  = c0 + 16 * cc;
            const int d0 = (c ^ X) >> 1;
            floatx4 f0 = *(const floatx4*)(kg + grow + d0);
            floatx4 f1 = *(const floatx4*)(kg + grow + d0 + 4);
            uintx4 pk = (uintx4){ f2bf(f0[0]) | (f2bf(f0[1]) << 16),
                                  f2bf(f0[2]) | (f2bf(f0[3]) << 16),
                                  f2bf(f1[0]) | (f2bf(f1[1]) << 16),
                                  f2bf(f1[2]) | (f2bf(f1[3]) << 16) };
            *(uintx4*)(kpre + t * 8192 + r * 128 + c) = pk;
        }
    }
    // V: load rows coalesced, zero pad-masked rows, transpose into LDS
    {
        const int key = tid >> 2;
        const int d0  = (tid & 3) * 16;
        const float vz = mg[(size_t)b * S_LEN + t * 64 + key] ? 1.f : 0.f;
        const size_t grow = (((size_t)b * S_LEN + t * 64 + key) * NHEAD + h) * DHEAD;
        #pragma unroll
        for (int q = 0; q < 4; ++q) {
            floatx4 f = *(const floatx4*)(vg + grow + d0 + 4 * q);
            #pragma unroll
            for (int ii = 0; ii < 4; ++ii)
                Tl[(d0 + 4 * q + ii) * 72 + key] = (unsigned short)f2bf(f[ii] * vz);
        }
    }
    __syncthreads();
    // V out: swizzled 16B chunks, keys gathered in interleaved storage order
    {
        const int d  = tid >> 2;
        const int c0 = (tid & 3) * 32;
        const int Xv = (d & 7) << 4;
        #pragma unroll
        for (int cc = 0; cc < 2; ++cc) {
            const int c   = c0 + 16 * cc;      // physical byte pos in 128B row
            const int pp0 = (c ^ Xv) >> 1;     // logical halfword pos (mult of 8)
            const int blk = pp0 >> 5;
            const int a   = (pp0 & 31) >> 3;
            unsigned short vals[8];
            #pragma unroll
            for (int i = 0; i < 8; ++i) {
                const int key = 32 * blk + ((i < 4) ? (4 * a + i) : (16 + 4 * a + i - 4));
                vals[i] = Tl[d * 72 + key];
            }
            *(uintx4*)(vpre + t * 8192 + d * 128 + c) = *(const uintx4*)vals;
        }
    }
    // mask frags: bf16 1.0/0.0 at slot (g,ks,i) matching pa's key map
    if (h == 0 && tid < 64) {
        const int key = tid;
        const int gg = (key >> 2) & 3, lo = key & 3;
        const int ks = key >> 5,      hi = (key >> 4) & 1;
        const unsigned short mv = mg[(size_t)b * S_LEN + t * 64 + key] ? 0x3F80 : 0;
        *(unsigned short*)(ws + MOFF + (size_t)b * 4096 + t * 128
                           + gg * 32 + ks * 16 + (4 * hi + lo) * 2) = mv;
    }
}

// ---------------------------------------------------------------------------
// Main: 128 q-rows/block, 8 waves = 4wq x 2kh, grp=2 (wave: 32 q x 32 keys).
// 3-buffer K/V staging via global_load_lds, counted vmcnt(2) + raw s_barrier
// (never drain to 0 mid-loop). Fixed-max softmax (m=8 via persistent NEG8 as
// MFMA C-init); den via mask-MFMA; mask frags register-prefetched.
// ---------------------------------------------------------------------------
__global__ __launch_bounds__(512, 4) void fa3_main(
    const float* __restrict__ qg, const char* __restrict__ ws,
    float* __restrict__ og)
{
    __shared__ char smem[65536];
    unsigned short* Qs = (unsigned short*)smem;          // 16 KB [128*64]
    char* KsB = smem + 16384;                            // 3 x 8 KB
    char* VsB = smem + 40960;                            // 3 x 8 KB

    const int tid  = threadIdx.x;
    const int bid  = blockIdx.x;
    // balanced pairing: bid and bid+256 co-reside (XCD rr); qb sums ~const.
    const int b    = bid >> 8;
    const int bh   = (b << 4) | (bid & 15);
    const int rpair= (bid >> 4) & 15;
    const int qb   = b ? rpair : 15 - rpair;
    const int h    = bh & 15;
    const int w    = tid >> 6;               // wave 0..7
    const int lane = tid & 63;
    const int g    = lane >> 4;
    const int lm   = lane & 15;
    const int kh   = w >> 2;                 // key half 0/1 (32 keys)
    const int wq   = w & 3;                  // q sub-block: rows [32wq, 32wq+32)
    const char* kpre = ws + (size_t)bh * PL_BYTES;
    const char* vpre = ws + VOFF + (size_t)bh * PL_BYTES;
    const char* mgf  = ws + MOFF + (size_t)b * 4096;
    const int nkt = (qb == 0) ? 2 : (2 * qb + 2);

    // stage tile 0 into buffer 0 (DMA overlaps Q normalize)
    GLOAD_LDS16(kpre + tid * 16, KsB + tid * 16);
    GLOAD_LDS16(vpre + tid * 16, VsB + tid * 16);

    // stage Q: load fp32, L2-normalize * 0.125 * log2(e), bf16, swizzled
    {
        const int r  = tid >> 2;             // q-row 0..127
        const int q0 = tid & 3;
        const float* src = qg + (((size_t)b * S_LEN + (size_t)qb * 128 + r) * NHEAD + h) * DHEAD + q0 * 16;
        floatx4 f0 = *(const floatx4*)(src + 0);
        floatx4 f1 = *(const floatx4*)(src + 4);
        floatx4 f2 = *(const floatx4*)(src + 8);
        floatx4 f3 = *(const floatx4*)(src + 12);
        float ssq = 0.f;
        #pragma unroll
        for (int i = 0; i < 4; ++i)
            ssq += f0[i]*f0[i] + f1[i]*f1[i] + f2[i]*f2[i] + f3[i]*f3[i];
        ssq += __shfl_xor(ssq, 1);
        ssq += __shfl_xor(ssq, 2);
        const float sc = (0.125f * LOG2E) / fmaxf(sqrtf(ssq), 1e-12f);
        float fv[16];
        #pragma unroll
        for (int i = 0; i < 4; ++i) { fv[i]=f0[i]; fv[4+i]=f1[i]; fv[8+i]=f2[i]; fv[12+i]=f3[i]; }
        unsigned pk[8];
        #pragma unroll
        for (int i = 0; i < 8; ++i)
            pk[i] = cvtpk(fv[2*i]*sc, fv[2*i+1]*sc);
        const int X = (r & 7) << 4;
        char* qp = (char*)Qs + r * 128;
        *(uintx4*)(qp + ((32*q0)      ^ X)) = (uintx4){pk[0],pk[1],pk[2],pk[3]};
        *(uintx4*)(qp + ((32*q0 + 16) ^ X)) = (uintx4){pk[4],pk[5],pk[6],pk[7]};
    }
    __syncthreads();                         // Qs + tile 0 visible (full drain, once)

    const int Xl = (lm & 7) << 4;
    // per-lane Q fragments: 2 q-groups (rows 32wq+16grp+lm), contiguous d-map
    short8 qf[2][2];
    #pragma unroll
    for (int grp = 0; grp < 2; ++grp) {
        const int row = wq * 32 + grp * 16 + lm;
        const char* base = (const char*)Qs + row * 128;
        #pragma unroll
        for (int ksd = 0; ksd < 2; ++ksd)
            qf[grp][ksd] = *(const short8*)(base + ((64*ksd + 16*g) ^ Xl));
    }

    // prefetch mask(0) then KV(1) -> buffer 1 (issue order matters for vmcnt)
    short8 mfn = *(const short8*)(mgf + 0 * 128 + g * 32 + kh * 16);
    if (nkt > 1) {
        GLOAD_LDS16(kpre + 8192 + tid * 16, KsB + 8192 + tid * 16);
        GLOAD_LDS16(vpre + 8192 + tid * 16, VsB + 8192 + tid * 16);
    }

    floatx4 oacc[2][4];
    floatx4 dacc[2];
    #pragma unroll
    for (int grp = 0; grp < 2; ++grp) {
        dacc[grp] = (floatx4){0.f,0.f,0.f,0.f};
        #pragma unroll
        for (int nt = 0; nt < 4; ++nt) oacc[grp][nt] = (floatx4){0.f,0.f,0.f,0.f};
    }
    floatx4 NEG8 = (floatx4){-8.f,-8.f,-8.f,-8.f};
    asm volatile("" : "+v"(NEG8));           // keep live: MFMA C-init, no per-tile movs
    const int qgl0 = qb * 128 + wq * 32 + lm;

    int cur = 0;
    for (int kt = 0; kt < nkt; ++kt) {
        // counted wait: [KV(kt):2, mask(kt):1, KV(kt+1):2] in flight ->
        // vmcnt(2) drains exactly KV(kt)+mask(kt); last iter drains all.
        if (kt + 1 < nkt) { asm volatile("s_waitcnt vmcnt(2)" ::: "memory"); }
        else              { asm volatile("s_waitcnt vmcnt(0)" ::: "memory"); }
        __builtin_amdgcn_s_barrier();
        __builtin_amdgcn_sched_barrier(0);

        const short8 mf = mfn;
        // issue mask(kt+1) BEFORE KV(kt+2) (keeps the vmcnt ordering exact)
        if (kt + 1 < nkt)
            mfn = *(const short8*)(mgf + (kt + 1) * 128 + g * 32 + kh * 16);
        if (kt + 2 < nkt) {
            int nb = cur + 2; if (nb >= 3) nb -= 3;
            const size_t tb = (size_t)(kt + 2) * 8192;
            GLOAD_LDS16(kpre + tb + tid * 16, KsB + nb * 8192 + tid * 16);
            GLOAD_LDS16(vpre + tb + tid * 16, VsB + nb * 8192 + tid * 16);
        }

        // ---- swapped QK^T on this wave's key half; C-init = NEG8 ----
        floatx4 st[2][2];
        const char* kbase = KsB + cur * 8192 + kh * 4096 + lm * 128;
        __builtin_amdgcn_s_setprio(1);
        #pragma unroll
        for (int mt = 0; mt < 2; ++mt) {
            short8 kf = *(const short8*)(kbase + mt * 2048 + ((16*g) ^ Xl));
            st[0][mt] = mfma16(kf, qf[0][0], NEG8);
            st[1][mt] = mfma16(kf, qf[1][0], NEG8);
        }
        #pragma unroll
        for (int mt = 0; mt < 2; ++mt) {
            short8 kf = *(const short8*)(kbase + mt * 2048 + ((64 + 16*g) ^ Xl));
            st[0][mt] = mfma16(kf, qf[0][1], st[0][mt]);
            st[1][mt] = mfma16(kf, qf[1][1], st[1][mt]);
        }
        __builtin_amdgcn_s_setprio(0);

        // ---- causal (diagonal tiles only: kt in {2qb, 2qb+1}, qb>=1) ----
        if ((qb >= 1) && (kt >= 2 * qb)) {
            #pragma unroll
            for (int mt = 0; mt < 2; ++mt)
                #pragma unroll
                for (int j = 0; j < 4; ++j) {
                    const int kgl = kt * KB + kh * 32 + mt * 16 + 4 * g + j;
                    if (kgl > qgl0)      st[0][mt][j] = -10000.f;
                    if (kgl > qgl0 + 16) st[1][mt][j] = -10000.f;
                }
        }

        // ---- p = exp2(st); pack; den-MFMA + PV-MFMA ----
        short8 pa[2];
        #pragma unroll
        for (int grp = 0; grp < 2; ++grp) {
            float p[8];
            #pragma unroll
            for (int mt = 0; mt < 2; ++mt)
                #pragma unroll
                for (int j = 0; j < 4; ++j)
                    p[mt * 4 + j] = exp2f(st[grp][mt][j]);
            union { short8 s; uintx4 u; } pu;
            pu.u = (uintx4){ cvtpk(p[0], p[1]), cvtpk(p[2], p[3]),
                             cvtpk(p[4], p[5]), cvtpk(p[6], p[7]) };
            pa[grp] = pu.s;
        }
        __builtin_amdgcn_s_setprio(1);
        dacc[0] = mfma16(pa[0], mf, dacc[0]);
        dacc[1] = mfma16(pa[1], mf, dacc[1]);
        {
            const char* vbase = VsB + cur * 8192 + lm * 128;
            #pragma unroll
            for (int nt = 0; nt < 4; ++nt) {
                short8 vf = *(const short8*)(vbase + nt * 2048 + ((64*kh + 16*g) ^ Xl));
                oacc[0][nt] = mfma16(pa[0], vf, oacc[0][nt]);
                oacc[1][nt] = mfma16(pa[1], vf, oacc[1][nt]);
            }
        }
        __builtin_amdgcn_s_setprio(0);

        cur += 1; if (cur >= 3) cur -= 3;
    }
    __syncthreads();                         // all waves done reading K/V bufs

    // ---- combine key halves: kh=1 dumps to LDS (compact 32KB), kh=0 sums ----
    floatx4* rbuf = (floatx4*)(smem + 16384);   // 48 KB region, use 32 KB
    float*   dbuf = (float*)smem;               // 512 B (Qs region, dead now)
    if (kh == 1) {
        #pragma unroll
        for (int grp = 0; grp < 2; ++grp)
            #pragma unroll
            for (int nt = 0; nt < 4; ++nt)
                rbuf[((grp * 4 + nt) * 4 + wq) * 64 + lane] = oacc[grp][nt];
    }
    __syncthreads();
    if (kh == 0) {
        #pragma unroll
        for (int grp = 0; grp < 2; ++grp)
            #pragma unroll
            for (int nt = 0; nt < 4; ++nt)
                oacc[grp][nt] += rbuf[((grp * 4 + nt) * 4 + wq) * 64 + lane];
    }
    __syncthreads();
    if (kh == 1 && lm == 0) {
        #pragma unroll
        for (int grp = 0; grp < 2; ++grp)
            #pragma unroll
            for (int j = 0; j < 4; ++j)
                dbuf[wq * 32 + grp * 16 + 4 * g + j] = dacc[grp][j];
    }
    __syncthreads();
    if (kh == 0) {
        #pragma unroll
        for (int grp = 0; grp < 2; ++grp)
            #pragma unroll
            for (int j = 0; j < 4; ++j) {
                const float den = dacc[grp][j] + dbuf[wq * 32 + grp * 16 + 4 * g + j];
                const float invj = 1.0f / den;
                const int row = qb * 128 + wq * 32 + grp * 16 + 4 * g + j;
                float* dst = og + (((size_t)b * S_LEN + row) * NHEAD + h) * DHEAD + lm;
                #pragma unroll
                for (int nt = 0; nt < 4; ++nt) dst[nt * 16] = oacc[grp][nt][j] * invj;
            }
    }
}

// ---------------------------------------------------------------------------
// Fallback (round-2 kernel, known-good) if ws_size is too small.
// ---------------------------------------------------------------------------
__global__ __launch_bounds__(512) void fa3_fallback(
    const float* __restrict__ qg, const float* __restrict__ kg,
    const float* __restrict__ vg, const int* __restrict__ mg,
    float* __restrict__ og)
{
    __shared__ unsigned short Qs[128 * DHEAD];
    __shared__ unsigned short Ks2[KB * DHEAD];
    __shared__ unsigned short Vt[DHEAD * KB];
    __shared__ float Ms[KB];

    const int tid  = threadIdx.x;
    const int bid  = blockIdx.x;
    const int qb   = 15 - (bid >> 5);
    const int bh   = bid & 31;
    const int b    = bh >> 4;
    const int h    = bh & 15;
    const int w    = tid >> 6;
    const int lane = tid & 63;
    const int g    = lane >> 4;
    const int lm   = lane & 15;

    {
        const int r  = tid >> 2;
        const int q0 = tid & 3;
        const float* src = qg + (((size_t)b * S_LEN + (size_t)qb * 128 + r) * NHEAD + h) * DHEAD + q0 * 16;
        floatx4 f0 = *(const floatx4*)(src + 0);
        floatx4 f1 = *(const floatx4*)(src + 4);
        floatx4 f2 = *(const floatx4*)(src + 8);
        floatx4 f3 = *(const floatx4*)(src + 12);
        float ssq = 0.f;
        #pragma unroll
        for (int i = 0; i < 4; ++i)
            ssq += f0[i]*f0[i] + f1[i]*f1[i] + f2[i]*f2[i] + f3[i]*f3[i];
        ssq += __shfl_xor(ssq, 1);
        ssq += __shfl_xor(ssq, 2);
        const float sc = 0.125f / fmaxf(sqrtf(ssq), 1e-12f);
        float fv[16];
        #pragma unroll
        for (int i = 0; i < 4; ++i) { fv[i]=f0[i]; fv[4+i]=f1[i]; fv[8+i]=f2[i]; fv[12+i]=f3[i]; }
        unsigned pk[8];
        #pragma unroll
        for (int i = 0; i < 8; ++i)
            pk[i] = f2bf(fv[2*i]*sc) | (f2bf(fv[2*i+1]*sc) << 16);
        const int X = (r & 7) << 4;
        char* qp = (char*)Qs + r * 128;
        *(uintx4*)(qp + ((32*q0)      ^ X)) = (uintx4){pk[0],pk[1],pk[2],pk[3]};
        *(uintx4*)(qp + ((32*q0 + 16) ^ X)) = (uintx4){pk[4],pk[5],pk[6],pk[7]};
    }
    __syncthreads();

    short8 qf[2];
    {
        const int row = w * 16 + lm;
        const int X = (row & 7) << 4;
        const char* base = (const char*)Qs + row * 128;
        #pragma unroll
        for (int ks = 0; ks < 2; ++ks) {
            union { short8 s; uintx2 u[2]; } u;
            u.u[0] = *(const uintx2*)(base + ((64*ks + 8*g)      ^ X));
            u.u[1] = *(const uintx2*)(base + ((64*ks + 8*g + 32) ^ X));
            qf[ks] = u.s;
        }
    }

    floatx4 oacc[4];
    #pragma unroll
    for (int nt = 0; nt < 4; ++nt) oacc[nt] = (floatx4){0.f,0.f,0.f,0.f};
    float mrun = NEGINF, lrun = 0.f;
    const int q_glob = qb * 128 + w * 16 + lm;
    const int nkt = (qb == 0) ? 2 : (2 * qb + 2);

    for (int kt = 0; kt < nkt; ++kt) {
        const int kb0 = kt * KB;
        {
            const int r = tid >> 3;
            const int o = tid & 7;
            const size_t goff = (((size_t)b * S_LEN + kb0 + r) * NHEAD + h) * DHEAD + o * 8;
            floatx4 a0 = *(const floatx4*)(kg + goff);
            floatx4 a1 = *(const floatx4*)(kg + goff + 4);
            floatx4 c0 = *(const floatx4*)(vg + goff);
            floatx4 c1 = *(const floatx4*)(vg + goff + 4);
            uintx4 kw = (uintx4){ f2bf(a0[0]) | (f2bf(a0[1])<<16),
                                  f2bf(a0[2]) | (f2bf(a0[3])<<16),
                                  f2bf(a1[0]) | (f2bf(a1[1])<<16),
                                  f2bf(a1[2]) | (f2bf(a1[3])<<16) };
            *(uintx4*)((char*)Ks2 + r*128 + ((16*o) ^ ((r & 7) << 4))) = kw;
            float cv[8];
            #pragma unroll
            for (int i = 0; i < 4; ++i) { cv[i] = c0[i]; cv[4+i] = c1[i]; }
            #pragma unroll
            for (int i = 0; i < 8; ++i) {
                const int d = 8*o + i;
                Vt[d*64 + (r ^ (((i ^ o) & 7) << 3))] = (unsigned short)f2bf(cv[i]);
            }
            if (tid < KB) Ms[tid] = mg[(size_t)b * S_LEN + kb0 + tid] ? 0.f : NEGINF;
        }
        __syncthreads();

        floatx4 st[4];
        #pragma unroll
        for (int mt = 0; mt < 4; ++mt) st[mt] = (floatx4){0.f,0.f,0.f,0.f};
        #pragma unroll
        for (int ks = 0; ks < 2; ++ks) {
            #pragma unroll
            for (int mt = 0; mt < 4; ++mt) {
                const int row = mt * 16 + lm;
                const int X = (row & 7) << 4;
                const char* base = (const char*)Ks2 + row * 128;
                union { short8 s; uintx2 u[2]; } u;
                u.u[0] = *(const uintx2*)(base + ((64*ks + 8*g)      ^ X));
                u.u[1] = *(const uintx2*)(base + ((64*ks + 8*g + 32) ^ X));
                st[mt] = mfma16(u.s, qf[ks], st[mt]);
            }
        }

        const bool diag = (qb > 0) && (kt >= 2 * qb);
        float sv[16];
        #pragma unroll
        for (int mt = 0; mt < 4; ++mt) {
            #pragma unroll
            for (int j = 0; j < 4; ++j) {
                const int kl = mt * 16 + 4 * g + j;
                float s = st[mt][j] + Ms[kl];
                if (diag && (kb0 + kl > q_glob)) s = NEGINF;
                sv[mt * 4 + j] = s;
            }
        }

        float rmax = sv[0];
        #pragma unroll
        for (int i = 1; i < 16; ++i) rmax = fmaxf(rmax, sv[i]);
        rmax = fmaxf(rmax, __shfl_xor(rmax, 16));
        rmax = fmaxf(rmax, __shfl_xor(rmax, 32));
        const float mnew = fmaxf(mrun, rmax);
        const float cf = __expf(mrun - mnew);
        float p[16], psum = 0.f;
        #pragma unroll
        for (int i = 0; i < 16; ++i) { p[i] = __expf(sv[i] - mnew); psum += p[i]; }
        psum += __shfl_xor(psum, 16);
        psum += __shfl_xor(psum, 32);
        lrun = lrun * cf + psum;
        mrun = mnew;

        float cj[4];
        #pragma unroll
        for (int j = 0; j < 4; ++j) cj[j] = __shfl(cf, 20 * g + j);
        #pragma unroll
        for (int nt = 0; nt < 4; ++nt)
            #pragma unroll
            for (int j = 0; j < 4; ++j) oacc[nt][j] *= cj[j];

        short8 pa[2];
        #pragma unroll
        for (int ks = 0; ks < 2; ++ks)
            #pragma unroll
            for (int i = 0; i < 8; ++i)
                pa[ks][i] = (short)f2bf(p[(2*ks + (i>>2))*4 + (i&3)]);

        #pragma unroll
        for (int nt = 0; nt < 4; ++nt) {
            const int d = 16 * nt + lm;
            const int xz = (((d & 7) ^ ((d >> 3) & 7)) & 7) << 4;
            const char* vb = (const char*)Vt + d * 128;
            #pragma unroll
            for (int ks = 0; ks < 2; ++ks) {
                union { short8 s; uintx2 u[2]; } vu;
                vu.u[0] = *(const uintx2*)(vb + ((64*ks + 8*g)      ^ xz));
                vu.u[1] = *(const uintx2*)(vb + ((64*ks + 8*g + 32) ^ xz));
                oacc[nt] = mfma16(pa[ks], vu.s, oacc[nt]);
            }
        }
        __syncthreads();
    }

    const float inv = 1.0f / lrun;
    #pragma unroll
    for (int j = 0; j < 4; ++j) {
        const float invj = __shfl(inv, 20 * g + j);
        const int row = qb * 128 + w * 16 + 4 * g + j;
        float* dst = og + (((size_t)b * S_LEN + row) * NHEAD + h) * DHEAD + lm;
        #pragma unroll
        for (int nt = 0; nt < 4; ++nt) dst[nt * 16] = oacc[nt][j] * invj;
    }
}

extern "C" void kernel_launch(void* const* d_in, const int* in_sizes, int n_in,
                              void* d_out, int out_size, void* d_ws, size_t ws_size,
                              hipStream_t stream)
{
    const float* q = (const float*)d_in[0];
    const float* k = (const float*)d_in[1];
    const float* v = (const float*)d_in[2];
    const int*   m = (const int*)d_in[3];
    float* out = (float*)d_out;
    (void)in_sizes; (void)n_in; (void)out_size;
    if (ws_size >= WS_NEEDED) {
        prep_kernel<<<dim3(1024), dim3(256), 0, stream>>>(k, v, m, (char*)d_ws);
        fa3_main<<<dim3(512), dim3(512), 0, stream>>>(q, (const char*)d_ws, out);
    } else {
        fa3_fallback<<<dim3(512), dim3(512), 0, stream>>>(q, k, v, m, out);
    }
}